// Round 21
// baseline (134.836 us; speedup 1.0000x reference)
//
#include <hip/hip_runtime.h>
#include <hip/hip_fp16.h>
#include <stdint.h>

#define N_GROUPS 368
#define NMODELS  64
#define BATCH    4096
#define RPB      64    // rows per block
#define GPB      2     // groups per block -> 512B contiguous per row

typedef __attribute__((ext_vector_type(8)))  _Float16 half8v;
typedef __attribute__((ext_vector_type(4)))  _Float16 half4v;
typedef __attribute__((ext_vector_type(16))) float    f32x16;

// W (fp16 halves): halfword-offset XOR swizzle (verified R7..R20)
#define SWZ(row, soff) ((soff) ^ (((row) & 7) << 3))
// X slab: 5-bit 16B-slot XOR swizzle over 32 slots/row
#define XS5(row, slot) ((slot) ^ ((row) & 31))

__global__ __launch_bounds__(256, 2) void ensemble_g2(
    const float* __restrict__ x,     // [BATCH][N_GROUPS][NMODELS]
    const float* __restrict__ W,     // [N_GROUPS][NMODELS][NMODELS]
    const float* __restrict__ bias,  // [N_GROUPS][NMODELS]
    float* __restrict__ out)         // [BATCH][N_GROUPS]
{
    __shared__ float    Xs[RPB * 128];     // 32 KB  [row][2 groups x 64 floats]
    __shared__ _Float16 Wh[GPB][64 * 64];  // 16 KB fp16 hi of W (both groups)
    __shared__ _Float16 Wl[GPB][64 * 64];  // 16 KB fp16 residual -> 64 KB, 2/CU

    const int g0   = blockIdx.y * GPB;
    const int row0 = blockIdx.x * RPB;
    const int t    = threadIdx.x;
    const int lane = t & 63;
    const int wv   = t >> 6;

    // ---- async X stage: each instr = 1 KB = 2 rows x 512B CONTIGUOUS ----
    // wave wv stages slab rows [wv*16, wv*16+16). Lane l -> row +(l>>5),
    // physical slot l&31. Physical slot p holds logical slot p^(r&31)
    // (inverse-swizzled source; linear LDS dest per m104).
    {
        const int rl = lane >> 5;          // row within the 2-row pair
        const int p  = lane & 31;          // physical 16B slot
        #pragma unroll
        for (int j = 0; j < 8; ++j) {
            const int r = wv * 16 + 2 * j + rl;   // slab row
            const int q = XS5(r, p);              // logical (source) slot
            const float* gsrc =
                x + ((size_t)(row0 + r) * N_GROUPS + g0) * NMODELS + 4 * q;
            __builtin_amdgcn_global_load_lds(
                (const __attribute__((address_space(1))) void*)gsrc,
                (__attribute__((address_space(3))) void*)&Xs[(wv * 16 + 2 * j) * 128],
                16, 0, 0);
        }
    }

    // ---- stage W[g0..g0+1] -> fp16 hi/lo (32 floats/thread) ----
    {
        const int gws = t >> 7;            // group 0..1
        const int u   = t & 127;
        const int m   = u >> 1;            // W row 0..63
        const int wc  = (u & 1) * 32;      // half-row of 32 floats
        const float* __restrict__ Wgp = W + ((size_t)(g0 + gws) * 64 + m) * 64 + wc;
        #pragma unroll
        for (int j = 0; j < 8; ++j) {
            const float4 v = *reinterpret_cast<const float4*>(Wgp + 4 * j);
            half4v h, l;
            h[0]=(_Float16)v.x; l[0]=(_Float16)(v.x-(float)h[0]);
            h[1]=(_Float16)v.y; l[1]=(_Float16)(v.y-(float)h[1]);
            h[2]=(_Float16)v.z; l[2]=(_Float16)(v.z-(float)h[2]);
            h[3]=(_Float16)v.w; l[3]=(_Float16)(v.w-(float)h[3]);
            const int so = m * 64 + SWZ(m, wc + 4 * j);
            *reinterpret_cast<half4v*>(&Wh[gws][so]) = h;
            *reinterpret_cast<half4v*>(&Wl[gws][so]) = l;
        }
    }
    __syncthreads();   // drains DMA vmcnt; W visible

    // ---- per-wave compute: wave (gw, rt) owns rows rt*32..+32 of group gw ----
    const int cl   = lane & 31;
    const int h2   = lane >> 5;
    const int gw   = wv >> 1;
    const int rt   = wv & 1;
    const int srow = rt * 32 + cl;     // slab row for this lane
    const int g    = g0 + gw;

    f32x16 acc0, acc1;
    #pragma unroll
    for (int r = 0; r < 16; ++r) { acc0[r] = 0.f; acc1[r] = 0.f; }

    #pragma unroll
    for (int ks = 0; ks < 4; ++ks) {
        // X frag: logical slots e,e+1 of slab row srow (group gw's columns)
        const int e = gw * 16 + ks * 4 + 2 * h2;
        const float4 xa = *reinterpret_cast<const float4*>(&Xs[srow * 128 + 4 * XS5(srow, e)]);
        const float4 xb = *reinterpret_cast<const float4*>(&Xs[srow * 128 + 4 * XS5(srow, e + 1)]);
        half8v bh;
        bh[0]=(_Float16)xa.x; bh[1]=(_Float16)xa.y; bh[2]=(_Float16)xa.z; bh[3]=(_Float16)xa.w;
        bh[4]=(_Float16)xb.x; bh[5]=(_Float16)xb.y; bh[6]=(_Float16)xb.z; bh[7]=(_Float16)xb.w;

        const int ko = ks * 16 + 8 * h2;
        const int wo0 = cl * 64 + SWZ(cl, ko);              // tile 0: m = cl
        const half8v ah0 = *reinterpret_cast<const half8v*>(&Wh[gw][wo0]);
        const half8v al0 = *reinterpret_cast<const half8v*>(&Wl[gw][wo0]);
        acc0 = __builtin_amdgcn_mfma_f32_32x32x16_f16(ah0, bh, acc0, 0, 0, 0);
        acc0 = __builtin_amdgcn_mfma_f32_32x32x16_f16(al0, bh, acc0, 0, 0, 0);

        const int wo1 = (32 + cl) * 64 + SWZ(32 + cl, ko);  // tile 1: m = 32+cl
        const half8v ah1 = *reinterpret_cast<const half8v*>(&Wh[gw][wo1]);
        const half8v al1 = *reinterpret_cast<const half8v*>(&Wl[gw][wo1]);
        acc1 = __builtin_amdgcn_mfma_f32_32x32x16_f16(ah1, bh, acc1, 0, 0, 0);
        acc1 = __builtin_amdgcn_mfma_f32_32x32x16_f16(al1, bh, acc1, 0, 0, 0);
    }

    // ---- epilogue: bias inline, softmax over m, dot with EXACT fp32 x ----
    // lane's m-slots: m = tt*32 + 8*rq + 4*h2 + p ; acc reg r = 4*rq + p
    float y[2][16];
    #pragma unroll
    for (int tt = 0; tt < 2; ++tt)
        #pragma unroll
        for (int rq = 0; rq < 4; ++rq) {
            const float4 bv = *reinterpret_cast<const float4*>(
                bias + (size_t)g * 64 + tt * 32 + 8 * rq + 4 * h2);
            const f32x16& a = tt ? acc1 : acc0;
            y[tt][4*rq+0] = a[4*rq+0] + bv.x;
            y[tt][4*rq+1] = a[4*rq+1] + bv.y;
            y[tt][4*rq+2] = a[4*rq+2] + bv.z;
            y[tt][4*rq+3] = a[4*rq+3] + bv.w;
        }

    float mx = y[0][0];
    #pragma unroll
    for (int r = 1; r < 16; ++r) mx = fmaxf(mx, y[0][r]);
    #pragma unroll
    for (int r = 0; r < 16; ++r) mx = fmaxf(mx, y[1][r]);
    mx = fmaxf(mx, __shfl_xor(mx, 32));

    float S = 0.f, P = 0.f;
    #pragma unroll
    for (int tt = 0; tt < 2; ++tt)
        #pragma unroll
        for (int rq = 0; rq < 4; ++rq) {
            // x[srow][m], m-slot q = gw*16 + tt*8 + 2*rq + h2 : exact fp32
            const int q = gw * 16 + tt * 8 + 2 * rq + h2;
            const float4 xv4 = *reinterpret_cast<const float4*>(
                &Xs[srow * 128 + 4 * XS5(srow, q)]);
            const float e0 = __expf(y[tt][4*rq+0] - mx);
            const float e1 = __expf(y[tt][4*rq+1] - mx);
            const float e2 = __expf(y[tt][4*rq+2] - mx);
            const float e3 = __expf(y[tt][4*rq+3] - mx);
            S += (e0 + e1) + (e2 + e3);
            P = __builtin_fmaf(e0, xv4.x, P);
            P = __builtin_fmaf(e1, xv4.y, P);
            P = __builtin_fmaf(e2, xv4.z, P);
            P = __builtin_fmaf(e3, xv4.w, P);
        }
    S += __shfl_xor(S, 32);
    P += __shfl_xor(P, 32);

    if (h2 == 0)
        out[(size_t)(row0 + srow) * N_GROUPS + g] = P / S;
}

extern "C" void kernel_launch(void* const* d_in, const int* in_sizes, int n_in,
                              void* d_out, int out_size, void* d_ws, size_t ws_size,
                              hipStream_t stream) {
    const float* x  = (const float*)d_in[0];
    const float* W  = (const float*)d_in[1];
    const float* b  = (const float*)d_in[2];
    float* out = (float*)d_out;

    dim3 grid(BATCH / RPB, N_GROUPS / GPB);   // (64, 184)
    dim3 block(256);
    ensemble_g2<<<grid, block, 0, stream>>>(x, W, b, out);
}

// Round 22
// 98.667 us; speedup vs baseline: 1.3666x; 1.3666x over previous
//
#include <hip/hip_runtime.h>
#include <hip/hip_fp16.h>
#include <stdint.h>

#define N_GROUPS 368
#define NMODELS  64
#define BATCH    4096
#define WAVES    8
#define ROWS_BLK 256   // 8 waves x 32 rows

typedef __attribute__((ext_vector_type(8)))  _Float16 half8v;  // 8 fp16
typedef __attribute__((ext_vector_type(4)))  _Float16 half4v;
typedef __attribute__((ext_vector_type(16))) float    f32x16;  // 32x32 MFMA acc

// W (fp16 halves): halfword-offset XOR swizzle, verified R7..R21
#define SWZ(row, soff) ((soff) ^ (((row) & 7) << 3))
// X (fp32 slab): 16B-slot XOR swizzle, verified R16
#define XS(row, slot)  ((slot) ^ ((row) & 15))

__global__ __launch_bounds__(512, 4) void ensemble_dma(
    const float* __restrict__ x,     // [BATCH][N_GROUPS][NMODELS]
    const float* __restrict__ W,     // [N_GROUPS][NMODELS][NMODELS]
    const float* __restrict__ bias,  // [N_GROUPS][NMODELS]
    float* __restrict__ out)         // [BATCH][N_GROUPS]
{
    __shared__ float    Xs[WAVES][32 * 64];  // 64 KB fp32, slot-swizzled
    __shared__ _Float16 Wh[64 * 64];         //  8 KB fp16 hi of W
    __shared__ _Float16 Wl[64 * 64];         //  8 KB fp16 residual -> 80 KB, 2/CU

    const int g    = blockIdx.y;
    const int row0 = blockIdx.x * ROWS_BLK;
    const int t    = threadIdx.x;
    const int lane = t & 63;
    const int wv   = t >> 6;

    // ---- async X stage: each wave DMAs its own 32x64 fp32 slab (8 x 1KB) ----
    // chunk j = slab rows 4j..4j+3; lane i -> row 4j+(i>>4), PHYSICAL slot i&15.
    // physical slot p holds logical slot p ^ (row&15)  (inverse-swizzled source).
    {
        const int rloc = lane >> 4;           // 0..3 row within chunk
        const int p    = lane & 15;           // physical 16B slot
        #pragma unroll
        for (int j = 0; j < 8; ++j) {
            const int r = 4 * j + rloc;       // row within slab
            const int q = XS(r, p);           // logical (source) slot
            const float* gsrc =
                x + ((size_t)(row0 + wv * 32 + r) * N_GROUPS + g) * NMODELS + 4 * q;
            __builtin_amdgcn_global_load_lds(
                (const __attribute__((address_space(1))) void*)gsrc,
                (__attribute__((address_space(3))) void*)&Xs[wv][4 * j * 64],
                16, 0, 0);
        }
    }

    // ---- stage W[g] -> fp16 hi/lo (VALU; once per block; 8 floats/thread) ----
    {
        const int m  = t >> 3;           // W row 0..63
        const int wc = (t & 7) * 8;      // 8 floats
        const float* __restrict__ Wgp = W + ((size_t)g * 64 + m) * 64 + wc;
        const float4 v0 = *reinterpret_cast<const float4*>(Wgp);
        const float4 v1 = *reinterpret_cast<const float4*>(Wgp + 4);
        half4v h0, l0, h1, l1;
        h0[0]=(_Float16)v0.x; l0[0]=(_Float16)(v0.x-(float)h0[0]);
        h0[1]=(_Float16)v0.y; l0[1]=(_Float16)(v0.y-(float)h0[1]);
        h0[2]=(_Float16)v0.z; l0[2]=(_Float16)(v0.z-(float)h0[2]);
        h0[3]=(_Float16)v0.w; l0[3]=(_Float16)(v0.w-(float)h0[3]);
        h1[0]=(_Float16)v1.x; l1[0]=(_Float16)(v1.x-(float)h1[0]);
        h1[1]=(_Float16)v1.y; l1[1]=(_Float16)(v1.y-(float)h1[1]);
        h1[2]=(_Float16)v1.z; l1[2]=(_Float16)(v1.z-(float)h1[2]);
        h1[3]=(_Float16)v1.w; l1[3]=(_Float16)(v1.w-(float)h1[3]);
        const int s0 = m * 64 + SWZ(m, wc);
        const int s1 = m * 64 + SWZ(m, wc + 4);
        *reinterpret_cast<half4v*>(&Wh[s0]) = h0;
        *reinterpret_cast<half4v*>(&Wl[s0]) = l0;
        *reinterpret_cast<half4v*>(&Wh[s1]) = h1;
        *reinterpret_cast<half4v*>(&Wl[s1]) = l1;
    }
    __syncthreads();   // compiler drains vmcnt here -> all DMA chunks landed

    // ---- per-wave compute; no further barriers ----
    const int cl = lane & 31;     // slab row / W-row m base
    const int h2 = lane >> 5;     // k-half selector
    const float* __restrict__ slab = &Xs[wv][0];

    f32x16 acc0, acc1;
    #pragma unroll
    for (int r = 0; r < 16; ++r) { acc0[r] = 0.f; acc1[r] = 0.f; }

    #pragma unroll
    for (int ks = 0; ks < 4; ++ks) {
        // X frag: logical slots e, e+1 of row cl -> fp32 -> fp16
        const int e  = ks * 4 + 2 * h2;
        const float4 xa = *reinterpret_cast<const float4*>(&slab[cl * 64 + 4 * XS(cl, e)]);
        const float4 xb = *reinterpret_cast<const float4*>(&slab[cl * 64 + 4 * XS(cl, e + 1)]);
        half8v bh;
        bh[0]=(_Float16)xa.x; bh[1]=(_Float16)xa.y; bh[2]=(_Float16)xa.z; bh[3]=(_Float16)xa.w;
        bh[4]=(_Float16)xb.x; bh[5]=(_Float16)xb.y; bh[6]=(_Float16)xb.z; bh[7]=(_Float16)xb.w;

        const int ko = ks * 16 + 8 * h2;
        const int wo0 = cl * 64 + SWZ(cl, ko);              // tile 0: m = cl
        const half8v ah0 = *reinterpret_cast<const half8v*>(&Wh[wo0]);
        const half8v al0 = *reinterpret_cast<const half8v*>(&Wl[wo0]);
        acc0 = __builtin_amdgcn_mfma_f32_32x32x16_f16(ah0, bh, acc0, 0, 0, 0);
        acc0 = __builtin_amdgcn_mfma_f32_32x32x16_f16(al0, bh, acc0, 0, 0, 0);

        const int wo1 = (32 + cl) * 64 + SWZ(32 + cl, ko);  // tile 1: m = 32+cl
        const half8v ah1 = *reinterpret_cast<const half8v*>(&Wh[wo1]);
        const half8v al1 = *reinterpret_cast<const half8v*>(&Wl[wo1]);
        acc1 = __builtin_amdgcn_mfma_f32_32x32x16_f16(ah1, bh, acc1, 0, 0, 0);
        acc1 = __builtin_amdgcn_mfma_f32_32x32x16_f16(al1, bh, acc1, 0, 0, 0);
    }

    // ---- epilogue: bias inline, softmax over m, dot with EXACT fp32 x ----
    // lane's m-slots: m = tt*32 + 8*rq + 4*h2 + p ; acc reg r = 4*rq + p
    float y[2][16];
    #pragma unroll
    for (int tt = 0; tt < 2; ++tt)
        #pragma unroll
        for (int rq = 0; rq < 4; ++rq) {
            const float4 bv = *reinterpret_cast<const float4*>(
                bias + (size_t)g * 64 + tt * 32 + 8 * rq + 4 * h2);
            const f32x16& a = tt ? acc1 : acc0;
            y[tt][4*rq+0] = a[4*rq+0] + bv.x;
            y[tt][4*rq+1] = a[4*rq+1] + bv.y;
            y[tt][4*rq+2] = a[4*rq+2] + bv.z;
            y[tt][4*rq+3] = a[4*rq+3] + bv.w;
        }

    float mx = y[0][0];
    #pragma unroll
    for (int r = 1; r < 16; ++r) mx = fmaxf(mx, y[0][r]);
    #pragma unroll
    for (int r = 0; r < 16; ++r) mx = fmaxf(mx, y[1][r]);
    mx = fmaxf(mx, __shfl_xor(mx, 32));

    float S = 0.f, P = 0.f;
    #pragma unroll
    for (int tt = 0; tt < 2; ++tt)
        #pragma unroll
        for (int rq = 0; rq < 4; ++rq) {
            // x[cl][m], m-group slot q = tt*8 + 2*rq + h2 : exact fp32 from LDS
            const int q = tt * 8 + 2 * rq + h2;
            const float4 xv4 = *reinterpret_cast<const float4*>(
                &slab[cl * 64 + 4 * XS(cl, q)]);
            const float e0 = __expf(y[tt][4*rq+0] - mx);
            const float e1 = __expf(y[tt][4*rq+1] - mx);
            const float e2 = __expf(y[tt][4*rq+2] - mx);
            const float e3 = __expf(y[tt][4*rq+3] - mx);
            S += (e0 + e1) + (e2 + e3);
            P = __builtin_fmaf(e0, xv4.x, P);
            P = __builtin_fmaf(e1, xv4.y, P);
            P = __builtin_fmaf(e2, xv4.z, P);
            P = __builtin_fmaf(e3, xv4.w, P);
        }
    S += __shfl_xor(S, 32);
    P += __shfl_xor(P, 32);

    if (h2 == 0)
        out[(size_t)(row0 + wv * 32 + cl) * N_GROUPS + g] = P / S;
}

extern "C" void kernel_launch(void* const* d_in, const int* in_sizes, int n_in,
                              void* d_out, int out_size, void* d_ws, size_t ws_size,
                              hipStream_t stream) {
    const float* x  = (const float*)d_in[0];
    const float* W  = (const float*)d_in[1];
    const float* b  = (const float*)d_in[2];
    float* out = (float*)d_out;

    dim3 grid(BATCH / ROWS_BLK, N_GROUPS);   // (16, 368)
    dim3 block(512);
    ensemble_dma<<<grid, block, 0, stream>>>(x, W, b, out);
}